// Round 1
// baseline (4160.299 us; speedup 1.0000x reference)
//
#include <hip/hip_runtime.h>
#include <cstdint>
#include <cstddef>

#define B_SZ   4
#define N_PTS  16384
#define M_CENT 2048
#define NSAMP  32
#define C_IN   64
#define H1_DIM 64
#define H2_DIM 128
#define FPS_T  1024
#define PPT    (N_PTS / FPS_T)   // 16 points per thread
#define PAIRS  (PPT / 2)         // 8 SoA float2 pairs per thread
#define H0_STR 68                // 67 channels padded to 68 for 16B-aligned float4

typedef float v2f __attribute__((ext_vector_type(2)));

// ---------------------------------------------------------------------------
// K1: Farthest-point sampling. One block per batch, 1024 thr x 16 pts.
// Per-thread state is SoA-packed pairs: px/py/pz (8 x float2 = 48 VGPR) +
// pd (16 VGPR) = 64 data VGPRs + temps -> fits the 128-VGPR cap of
// launch_bounds(1024,4) with NO AGPR shuffling (round-3 pathology: 512thr x
// 32pts = 128 data floats, allocator split them into AGPRs -> ~2.5x VALU
// bloat from v_accvgpr_read/write, VGPR_Count=84, 73% VALU-busy on the 4
// active CUs). Inline-asm pins keep loads hoisted (round-2 pathology fix).
// Pair packing: 3 pk_sub + 3 pk_mul + 2 pk_add per 2 points, bit-identical
// per element to scalar ((dx*dx+dy*dy)+dz*dz) with contract(off).
// u64 (dist, N-idx) max-reduction == numpy argmax (max dist, min idx on tie).
// ---------------------------------------------------------------------------
__global__ __launch_bounds__(FPS_T, 4) void fps_kernel(const float* __restrict__ xyz,
                                                       float* __restrict__ out_xyz) {
#pragma clang fp contract(off)
  const int b    = blockIdx.x;
  const int t    = threadIdx.x;
  const int lane = t & 63;
  const int wave = t >> 6;           // 16 waves
  const float* bx = xyz + (size_t)b * N_PTS * 3;
  float* ox = out_xyz + (size_t)b * M_CENT * 3;

  v2f   px[PAIRS], py[PAIRS], pz[PAIRS];
  float pd[PPT];
#pragma unroll
  for (int k = 0; k < PAIRS; ++k) {
    const int i0 = (2 * k + 0) * FPS_T + t;
    const int i1 = (2 * k + 1) * FPS_T + t;
    v2f vx, vy, vz;
    vx.x = bx[i0 * 3 + 0]; vx.y = bx[i1 * 3 + 0];
    vy.x = bx[i0 * 3 + 1]; vy.y = bx[i1 * 3 + 1];
    vz.x = bx[i0 * 3 + 2]; vz.y = bx[i1 * 3 + 2];
    px[k] = vx; py[k] = vy; pz[k] = vz;
    pd[2 * k + 0] = 1e10f;  // BIG
    pd[2 * k + 1] = 1e10f;
  }
  // Pin: values now opaque-defined -> loads cannot be re-materialized in-loop.
#pragma unroll
  for (int k = 0; k < PAIRS; ++k) {
    asm volatile("" : "+v"(px[k]), "+v"(py[k]), "+v"(pz[k]));
  }

  __shared__ unsigned long long s_key[2][16];

  int cur = 0;  // reference idx0 = 0
  for (int m = 0; m < M_CENT; ++m) {
    const int curs = __builtin_amdgcn_readfirstlane(cur);  // uniform -> SGPR/s_load path
    const float cx = bx[curs * 3 + 0];                     // L2-hot broadcast
    const float cy = bx[curs * 3 + 1];
    const float cz = bx[curs * 3 + 2];
    if (t == 0) { ox[m * 3 + 0] = cx; ox[m * 3 + 1] = cy; ox[m * 3 + 2] = cz; }
    if (m == M_CENT - 1) break;

    v2f vcx, vcy, vcz;
    vcx.x = cx; vcx.y = cx;
    vcy.x = cy; vcy.y = cy;
    vcz.x = cz; vcz.y = cz;
    float bv = -1.0f;  // dists >= 0, so first point always taken
    int   bi = 0;
#pragma unroll
    for (int k = 0; k < PAIRS; ++k) {
      const v2f dx = px[k] - vcx;         // v_pk_sub_f32 (exact per element)
      const v2f dy = py[k] - vcy;
      const v2f dz = pz[k] - vcz;
      const v2f sx = dx * dx;             // v_pk_mul_f32
      const v2f sy = dy * dy;
      const v2f sz = dz * dz;
      const v2f s1 = sx + sy;             // v_pk_add_f32 -> (dx2+dy2)
      const v2f d2 = s1 + sz;             // -> (dx2+dy2)+dz2  (numpy op order, no FMA)
      const float nd0 = fminf(pd[2 * k + 0], d2.x);
      const float nd1 = fminf(pd[2 * k + 1], d2.y);
      pd[2 * k + 0] = nd0;
      pd[2 * k + 1] = nd1;
      // strict >: keeps smaller j (= smaller global idx) on ties within thread
      const bool b0 = nd0 > bv;
      bv = b0 ? nd0 : bv;
      bi = b0 ? ((2 * k + 0) * FPS_T + t) : bi;
      const bool b1 = nd1 > bv;
      bv = b1 ? nd1 : bv;
      bi = b1 ? ((2 * k + 1) * FPS_T + t) : bi;
    }
    // pack: high = float bits (>=0, monotone), low = N-idx so ties -> min idx
    unsigned long long key = ((unsigned long long)__float_as_uint(bv) << 32)
                           | (unsigned int)(N_PTS - bi);
#pragma unroll
    for (int off = 32; off >= 1; off >>= 1) {
      const unsigned long long o = __shfl_xor(key, off);
      key = (key > o) ? key : o;
    }
    const int p = m & 1;
    if (lane == 0) s_key[p][wave] = key;
    __syncthreads();
    // all waves redundantly reduce the 16 per-wave keys (no 2nd barrier)
    key = s_key[p][lane & 15];
#pragma unroll
    for (int off = 8; off >= 1; off >>= 1) {
      const unsigned long long o = __shfl_xor(key, off);
      key = (key > o) ? key : o;
    }
    cur = N_PTS - (int)(key & 0xFFFFFFFFULL);
  }
}

// ---------------------------------------------------------------------------
// K2: Ball query. One wave per centroid: ballot + prefix popcount appends the
// first 32 in-radius indices in index order (== top_k(-order) semantics),
// pads with the first hit. Early exit once 32 found.
// ---------------------------------------------------------------------------
__global__ __launch_bounds__(256) void ballq_kernel(const float* __restrict__ xyz,
                                                    const float* __restrict__ new_xyz,
                                                    int* __restrict__ idx_out) {
#pragma clang fp contract(off)
  const int lane = threadIdx.x & 63;
  const int gid  = blockIdx.x * 4 + (threadIdx.x >> 6);
  if (gid >= B_SZ * M_CENT) return;
  const int b = gid >> 11;  // / M_CENT
  const float* bx = xyz + (size_t)b * N_PTS * 3;
  const float cx = new_xyz[gid * 3 + 0];
  const float cy = new_xyz[gid * 3 + 1];
  const float cz = new_xyz[gid * 3 + 2];
  const float rr = (float)(0.8 * 0.8);  // double 0.64 -> f32 (JAX weak-scalar cast)
  int* out = idx_out + (size_t)gid * NSAMP;

  int count = 0;
  int first = -1;
  for (int base = 0; base < N_PTS; base += 64) {
    const int i = base + lane;
    const float dx = bx[i * 3 + 0] - cx;
    const float dy = bx[i * 3 + 1] - cy;
    const float dz = bx[i * 3 + 2] - cz;
    const float d = (dx * dx + dy * dy) + dz * dz;
    const bool pred = d < rr;
    const unsigned long long mk = __ballot(pred);
    if (pred) {
      const int slot = count + __popcll(mk & ((1ULL << lane) - 1ULL));
      if (slot < NSAMP) out[slot] = i;
    }
    if (first < 0 && mk != 0ULL) first = base + (__ffsll((long long)mk) - 1);
    count += __popcll(mk);
    if (count >= NSAMP) break;
  }
  if (count < NSAMP) {
    for (int k = count + lane; k < NSAMP; k += 64) out[k] = first;  // centroid itself is a hit
  }
}

// ---------------------------------------------------------------------------
// K3: gather + MLP(67->64 relu, 64->128 relu) + max over 32 samples.
// One 128-thread block per centroid. h0/h1 staged in LDS; reads are
// wave-uniform float4 broadcasts; weights coalesced from L1/L2.
// ---------------------------------------------------------------------------
__global__ __launch_bounds__(128) void mlp_kernel(const float* __restrict__ xyz,
                                                  const float* __restrict__ feats,
                                                  const float* __restrict__ new_xyz,
                                                  const int* __restrict__ idx,
                                                  const float* __restrict__ w1,
                                                  const float* __restrict__ b1,
                                                  const float* __restrict__ w2,
                                                  const float* __restrict__ b2,
                                                  float* __restrict__ out_feats) {
  const int gid = blockIdx.x;
  const int t   = threadIdx.x;
  const int b   = gid >> 11;  // / M_CENT

  __shared__ float h0[NSAMP * H0_STR];
  __shared__ float h1[NSAMP * H1_DIM];
  __shared__ int   sidx[NSAMP];

  if (t < NSAMP) sidx[t] = idx[(size_t)gid * NSAMP + t];
  const float cx = new_xyz[gid * 3 + 0];
  const float cy = new_xyz[gid * 3 + 1];
  const float cz = new_xyz[gid * 3 + 2];
  __syncthreads();

  const float* bxyz = xyz + (size_t)b * N_PTS * 3;
  const float* bft  = feats + (size_t)b * N_PTS * C_IN;
  for (int e = t; e < NSAMP * 67; e += 128) {
    const int s = e / 67;
    const int c = e - s * 67;
    const int p = sidx[s];
    float v;
    if (c < 3) {
      const float pc = bxyz[p * 3 + c];
      v = pc - (c == 0 ? cx : (c == 1 ? cy : cz));
    } else {
      v = bft[(size_t)p * C_IN + (c - 3)];
    }
    h0[s * H0_STR + c] = v;
  }
  __syncthreads();

  // layer 1: col = t&63 over H1_DIM, half = t>>6 picks 16 of 32 samples
  {
    const int col  = t & 63;
    const int half = t >> 6;
    float acc[16];
    const float bb = b1[col];
#pragma unroll
    for (int s = 0; s < 16; ++s) acc[s] = bb;
    const float* h0base = h0 + (half * 16) * H0_STR;
    for (int k = 0; k < 64; k += 4) {
      const float w0v = w1[(k + 0) * H1_DIM + col];
      const float w1v = w1[(k + 1) * H1_DIM + col];
      const float w2v = w1[(k + 2) * H1_DIM + col];
      const float w3v = w1[(k + 3) * H1_DIM + col];
#pragma unroll
      for (int s = 0; s < 16; ++s) {
        const float4 h4 = *reinterpret_cast<const float4*>(h0base + s * H0_STR + k);
        acc[s] += h4.x * w0v + h4.y * w1v + h4.z * w2v + h4.w * w3v;
      }
    }
    for (int k = 64; k < 67; ++k) {
      const float wv = w1[k * H1_DIM + col];
#pragma unroll
      for (int s = 0; s < 16; ++s) acc[s] += h0base[s * H0_STR + k] * wv;
    }
#pragma unroll
    for (int s = 0; s < 16; ++s) h1[(half * 16 + s) * H1_DIM + col] = fmaxf(acc[s], 0.0f);
  }
  __syncthreads();

  // layer 2 + max-pool: col = t over H2_DIM
  {
    float acc[32];
    const float bb = b2[t];
#pragma unroll
    for (int s = 0; s < 32; ++s) acc[s] = bb;
    for (int k = 0; k < 64; k += 4) {
      const float w0v = w2[(k + 0) * H2_DIM + t];
      const float w1v = w2[(k + 1) * H2_DIM + t];
      const float w2v = w2[(k + 2) * H2_DIM + t];
      const float w3v = w2[(k + 3) * H2_DIM + t];
#pragma unroll
      for (int s = 0; s < 32; ++s) {
        const float4 h4 = *reinterpret_cast<const float4*>(&h1[s * H1_DIM + k]);
        acc[s] += h4.x * w0v + h4.y * w1v + h4.z * w2v + h4.w * w3v;
      }
    }
    float mx = 0.0f;  // max(relu(v)) == max(0, max(v))
#pragma unroll
    for (int s = 0; s < 32; ++s) mx = fmaxf(mx, acc[s]);
    out_feats[(size_t)gid * H2_DIM + t] = mx;
  }
}

// ---------------------------------------------------------------------------
extern "C" void kernel_launch(void* const* d_in, const int* in_sizes, int n_in,
                              void* d_out, int out_size, void* d_ws, size_t ws_size,
                              hipStream_t stream) {
  const float* xyz   = (const float*)d_in[0];  // (4,16384,3) f32
  const float* feats = (const float*)d_in[1];  // (4,16384,64) f32
  // d_in[2] = bid (unused; output bid is all zeros)
  const float* w1 = (const float*)d_in[3];     // (67,64)
  const float* b1 = (const float*)d_in[4];     // (64,)
  const float* w2 = (const float*)d_in[5];     // (64,128)
  const float* b2 = (const float*)d_in[6];     // (128,)

  float* out       = (float*)d_out;
  float* out_xyz   = out;                                        // (4,2048,3)
  float* out_feats = out + (size_t)B_SZ * M_CENT * 3;            // (4,2048,128)
  float* out_bid   = out_feats + (size_t)B_SZ * M_CENT * H2_DIM; // (4,2048,1) int32 zeros
  int*   idx_ws    = (int*)d_ws;                                 // (4,2048,32) int32, 1 MiB

  hipLaunchKernelGGL(fps_kernel, dim3(B_SZ), dim3(FPS_T), 0, stream, xyz, out_xyz);
  hipLaunchKernelGGL(ballq_kernel, dim3((B_SZ * M_CENT + 3) / 4), dim3(256), 0, stream,
                     xyz, out_xyz, idx_ws);
  hipLaunchKernelGGL(mlp_kernel, dim3(B_SZ * M_CENT), dim3(128), 0, stream,
                     xyz, feats, out_xyz, idx_ws, w1, b1, w2, b2, out_feats);
  hipMemsetAsync(out_bid, 0, (size_t)B_SZ * M_CENT * sizeof(int), stream);
}

// Round 3
// 3708.257 us; speedup vs baseline: 1.1219x; 1.1219x over previous
//
#include <hip/hip_runtime.h>
#include <cstdint>
#include <cstddef>

#define B_SZ   4
#define N_PTS  16384
#define M_CENT 2048
#define NSAMP  32
#define C_IN   64
#define H1_DIM 64
#define H2_DIM 128
#define FPS_T  1024
#define PPT    (N_PTS / FPS_T)   // 16 points per thread
#define PAIRS  (PPT / 2)         // 8 SoA float2 pairs per thread
#define H0_STR 68                // 67 channels padded to 68 for 16B-aligned float4

typedef float v2f __attribute__((ext_vector_type(2)));

// u64 max with neighbor fetched via DPP (both 32-bit halves move from the same
// source lane; invalid lanes keep 'old' = self, i.e. identity under max).
// ~5 VALU per level at VALU latency -- replaces __shfl_xor's 2 ds_bpermute
// per level at ~LDS latency.
template <int CTRL>
__device__ __forceinline__ unsigned long long kmax_dpp(unsigned long long k) {
  const int lo  = (int)(unsigned)(k & 0xFFFFFFFFULL);
  const int hi  = (int)(unsigned)(k >> 32);
  const int olo = __builtin_amdgcn_update_dpp(lo, lo, CTRL, 0xF, 0xF, false);
  const int ohi = __builtin_amdgcn_update_dpp(hi, hi, CTRL, 0xF, 0xF, false);
  const unsigned long long o =
      ((unsigned long long)(unsigned)ohi << 32) | (unsigned)olo;
  return (o > k) ? o : k;
}

// ---------------------------------------------------------------------------
// K1: Farthest-point sampling. One block per batch, 1024 thr x 16 pts.
// Per-thread state: px/py/pz SoA pairs (48 VGPR) + pd (16 VGPR) = 64.
// Round-1 pathology: VGPR_Count=44 < 64 data floats -> read-only coord arrays
// were AGPR-assigned (unified file); every in-loop use paid v_accvgpr_read
// (~390 VALU instr/thread/iter measured vs ~200 source-level), so halving the
// arithmetic changed nothing. Fix A: per-iteration "+v" asm pins at m-loop
// top force px/py/pz to materialize in arch VGPRs each iteration -> AGPR
// residency becomes strictly more expensive than VGPR residency. Fix B:
// sched_barrier(0) per pair keeps temp live ranges short (peak pressure
// under the 128-VGPR cap of a 1024-thread block).
// Reduction: DPP u64-max (ROW_SHR 1/2/4/8 + BCAST15/31 -> lane63; cross-wave
// via LDS + ROW_SHR 1/2/4/8 -> readlane 15) -- u64 (dist, N-idx) key,
// bit-identical argmax (max dist, min idx on tie).
// Distance math: pk sub/mul/add, exact per element, numpy op order, no FMA.
// ---------------------------------------------------------------------------
__global__ __launch_bounds__(FPS_T, 4) void fps_kernel(const float* __restrict__ xyz,
                                                       float* __restrict__ out_xyz) {
#pragma clang fp contract(off)
  const int b    = blockIdx.x;
  const int t    = threadIdx.x;
  const int lane = t & 63;
  const int wave = t >> 6;           // 16 waves
  const float* bx = xyz + (size_t)b * N_PTS * 3;
  float* ox = out_xyz + (size_t)b * M_CENT * 3;

  v2f   px[PAIRS], py[PAIRS], pz[PAIRS];
  float pd[PPT];
#pragma unroll
  for (int k = 0; k < PAIRS; ++k) {
    const int i0 = (2 * k + 0) * FPS_T + t;
    const int i1 = (2 * k + 1) * FPS_T + t;
    v2f vx, vy, vz;
    vx.x = bx[i0 * 3 + 0]; vx.y = bx[i1 * 3 + 0];
    vy.x = bx[i0 * 3 + 1]; vy.y = bx[i1 * 3 + 1];
    vz.x = bx[i0 * 3 + 2]; vz.y = bx[i1 * 3 + 2];
    px[k] = vx; py[k] = vy; pz[k] = vz;
    pd[2 * k + 0] = 1e10f;  // BIG
    pd[2 * k + 1] = 1e10f;
  }

  __shared__ unsigned long long s_key[2][16];

  int cur = 0;  // reference idx0 = 0
  for (int m = 0; m < M_CENT; ++m) {
    // Per-iteration VGPR pins: values must sit in arch 'v' regs here, every
    // iteration -> allocator keeps them VGPR-resident (no accvgpr traffic).
    asm volatile("" : "+v"(px[0]), "+v"(px[1]), "+v"(px[2]), "+v"(px[3]),
                      "+v"(px[4]), "+v"(px[5]), "+v"(px[6]), "+v"(px[7]));
    asm volatile("" : "+v"(py[0]), "+v"(py[1]), "+v"(py[2]), "+v"(py[3]),
                      "+v"(py[4]), "+v"(py[5]), "+v"(py[6]), "+v"(py[7]));
    asm volatile("" : "+v"(pz[0]), "+v"(pz[1]), "+v"(pz[2]), "+v"(pz[3]),
                      "+v"(pz[4]), "+v"(pz[5]), "+v"(pz[6]), "+v"(pz[7]));

    const int curs = __builtin_amdgcn_readfirstlane(cur);  // uniform -> SGPR path
    const float cx = bx[curs * 3 + 0];                     // L2-hot broadcast
    const float cy = bx[curs * 3 + 1];
    const float cz = bx[curs * 3 + 2];
    if (t == 0) { ox[m * 3 + 0] = cx; ox[m * 3 + 1] = cy; ox[m * 3 + 2] = cz; }
    if (m == M_CENT - 1) break;

    v2f vcx, vcy, vcz;
    vcx.x = cx; vcx.y = cx;
    vcy.x = cy; vcy.y = cy;
    vcz.x = cz; vcz.y = cz;
    float bv = -1.0f;  // dists >= 0, so first point always taken
    int   bi = 0;
#pragma unroll
    for (int k = 0; k < PAIRS; ++k) {
      const v2f dx = px[k] - vcx;         // v_pk_sub_f32 (exact per element)
      const v2f dy = py[k] - vcy;
      const v2f dz = pz[k] - vcz;
      const v2f sx = dx * dx;             // v_pk_mul_f32
      const v2f sy = dy * dy;
      const v2f sz = dz * dz;
      const v2f s1 = sx + sy;             // v_pk_add_f32 -> (dx2+dy2)
      const v2f d2 = s1 + sz;             // -> (dx2+dy2)+dz2  (numpy op order, no FMA)
      const float nd0 = fminf(pd[2 * k + 0], d2.x);
      const float nd1 = fminf(pd[2 * k + 1], d2.y);
      pd[2 * k + 0] = nd0;
      pd[2 * k + 1] = nd1;
      // strict >: keeps smaller j (= smaller global idx) on ties within thread
      const bool c0 = nd0 > bv;
      bv = c0 ? nd0 : bv;
      bi = c0 ? ((2 * k + 0) * FPS_T + t) : bi;
      const bool c1 = nd1 > bv;
      bv = c1 ? nd1 : bv;
      bi = c1 ? ((2 * k + 1) * FPS_T + t) : bi;
      // Pin program order: keeps per-pair temps' live ranges short so the
      // allocator never exceeds the 128-VGPR cap (no AGPR round-trips).
      __builtin_amdgcn_sched_barrier(0);
    }
    // pack: high = float bits (>=0, monotone), low = N-idx so ties -> min idx
    unsigned long long key = ((unsigned long long)__float_as_uint(bv) << 32)
                           | (unsigned int)(N_PTS - bi);
    // intra-wave max -> lane 63 (other lanes hold partial maxes; only 63 used)
    key = kmax_dpp<0x111>(key);   // row_shr:1
    key = kmax_dpp<0x112>(key);   // row_shr:2
    key = kmax_dpp<0x114>(key);   // row_shr:4
    key = kmax_dpp<0x118>(key);   // row_shr:8
    key = kmax_dpp<0x142>(key);   // row_bcast15
    key = kmax_dpp<0x143>(key);   // row_bcast31
    const int p = m & 1;
    if (lane == 63) s_key[p][wave] = key;
    __syncthreads();
    // all waves redundantly reduce the 16 per-wave keys (no 2nd barrier):
    // each row of 16 lanes loads all 16 partials, ROW_SHR tree -> lane 15.
    unsigned long long k2 = s_key[p][lane & 15];
    k2 = kmax_dpp<0x111>(k2);
    k2 = kmax_dpp<0x112>(k2);
    k2 = kmax_dpp<0x114>(k2);
    k2 = kmax_dpp<0x118>(k2);
    const int lo15 = __builtin_amdgcn_readlane((int)(unsigned)(k2 & 0xFFFFFFFFULL), 15);
    cur = N_PTS - lo15;
  }
}

// ---------------------------------------------------------------------------
// K2: Ball query. One wave per centroid: ballot + prefix popcount appends the
// first 32 in-radius indices in index order (== top_k(-order) semantics),
// pads with the first hit. Early exit once 32 found.
// ---------------------------------------------------------------------------
__global__ __launch_bounds__(256) void ballq_kernel(const float* __restrict__ xyz,
                                                    const float* __restrict__ new_xyz,
                                                    int* __restrict__ idx_out) {
#pragma clang fp contract(off)
  const int lane = threadIdx.x & 63;
  const int gid  = blockIdx.x * 4 + (threadIdx.x >> 6);
  if (gid >= B_SZ * M_CENT) return;
  const int b = gid >> 11;  // / M_CENT
  const float* bx = xyz + (size_t)b * N_PTS * 3;
  const float cx = new_xyz[gid * 3 + 0];
  const float cy = new_xyz[gid * 3 + 1];
  const float cz = new_xyz[gid * 3 + 2];
  const float rr = (float)(0.8 * 0.8);  // double 0.64 -> f32 (JAX weak-scalar cast)
  int* out = idx_out + (size_t)gid * NSAMP;

  int count = 0;
  int first = -1;
  for (int base = 0; base < N_PTS; base += 64) {
    const int i = base + lane;
    const float dx = bx[i * 3 + 0] - cx;
    const float dy = bx[i * 3 + 1] - cy;
    const float dz = bx[i * 3 + 2] - cz;
    const float d = (dx * dx + dy * dy) + dz * dz;
    const bool pred = d < rr;
    const unsigned long long mk = __ballot(pred);
    if (pred) {
      const int slot = count + __popcll(mk & ((1ULL << lane) - 1ULL));
      if (slot < NSAMP) out[slot] = i;
    }
    if (first < 0 && mk != 0ULL) first = base + (__ffsll((long long)mk) - 1);
    count += __popcll(mk);
    if (count >= NSAMP) break;
  }
  if (count < NSAMP) {
    for (int k = count + lane; k < NSAMP; k += 64) out[k] = first;  // centroid itself is a hit
  }
}

// ---------------------------------------------------------------------------
// K3: gather + MLP(67->64 relu, 64->128 relu) + max over 32 samples.
// One 128-thread block per centroid. h0/h1 staged in LDS; reads are
// wave-uniform float4 broadcasts; weights coalesced from L1/L2.
// ---------------------------------------------------------------------------
__global__ __launch_bounds__(128) void mlp_kernel(const float* __restrict__ xyz,
                                                  const float* __restrict__ feats,
                                                  const float* __restrict__ new_xyz,
                                                  const int* __restrict__ idx,
                                                  const float* __restrict__ w1,
                                                  const float* __restrict__ b1,
                                                  const float* __restrict__ w2,
                                                  const float* __restrict__ b2,
                                                  float* __restrict__ out_feats) {
  const int gid = blockIdx.x;
  const int t   = threadIdx.x;
  const int b   = gid >> 11;  // / M_CENT

  __shared__ float h0[NSAMP * H0_STR];
  __shared__ float h1[NSAMP * H1_DIM];
  __shared__ int   sidx[NSAMP];

  if (t < NSAMP) sidx[t] = idx[(size_t)gid * NSAMP + t];
  const float cx = new_xyz[gid * 3 + 0];
  const float cy = new_xyz[gid * 3 + 1];
  const float cz = new_xyz[gid * 3 + 2];
  __syncthreads();

  const float* bxyz = xyz + (size_t)b * N_PTS * 3;
  const float* bft  = feats + (size_t)b * N_PTS * C_IN;
  for (int e = t; e < NSAMP * 67; e += 128) {
    const int s = e / 67;
    const int c = e - s * 67;
    const int p = sidx[s];
    float v;
    if (c < 3) {
      const float pc = bxyz[p * 3 + c];
      v = pc - (c == 0 ? cx : (c == 1 ? cy : cz));
    } else {
      v = bft[(size_t)p * C_IN + (c - 3)];
    }
    h0[s * H0_STR + c] = v;
  }
  __syncthreads();

  // layer 1: col = t&63 over H1_DIM, half = t>>6 picks 16 of 32 samples
  {
    const int col  = t & 63;
    const int half = t >> 6;
    float acc[16];
    const float bb = b1[col];
#pragma unroll
    for (int s = 0; s < 16; ++s) acc[s] = bb;
    const float* h0base = h0 + (half * 16) * H0_STR;
    for (int k = 0; k < 64; k += 4) {
      const float w0v = w1[(k + 0) * H1_DIM + col];
      const float w1v = w1[(k + 1) * H1_DIM + col];
      const float w2v = w1[(k + 2) * H1_DIM + col];
      const float w3v = w1[(k + 3) * H1_DIM + col];
#pragma unroll
      for (int s = 0; s < 16; ++s) {
        const float4 h4 = *reinterpret_cast<const float4*>(h0base + s * H0_STR + k);
        acc[s] += h4.x * w0v + h4.y * w1v + h4.z * w2v + h4.w * w3v;
      }
    }
    for (int k = 64; k < 67; ++k) {
      const float wv = w1[k * H1_DIM + col];
#pragma unroll
      for (int s = 0; s < 16; ++s) acc[s] += h0base[s * H0_STR + k] * wv;
    }
#pragma unroll
    for (int s = 0; s < 16; ++s) h1[(half * 16 + s) * H1_DIM + col] = fmaxf(acc[s], 0.0f);
  }
  __syncthreads();

  // layer 2 + max-pool: col = t over H2_DIM
  {
    float acc[32];
    const float bb = b2[t];
#pragma unroll
    for (int s = 0; s < 32; ++s) acc[s] = bb;
    for (int k = 0; k < 64; k += 4) {
      const float w0v = w2[(k + 0) * H2_DIM + t];
      const float w1v = w2[(k + 1) * H2_DIM + t];
      const float w2v = w2[(k + 2) * H2_DIM + t];
      const float w3v = w2[(k + 3) * H2_DIM + t];
#pragma unroll
      for (int s = 0; s < 32; ++s) {
        const float4 h4 = *reinterpret_cast<const float4*>(&h1[s * H1_DIM + k]);
        acc[s] += h4.x * w0v + h4.y * w1v + h4.z * w2v + h4.w * w3v;
      }
    }
    float mx = 0.0f;  // max(relu(v)) == max(0, max(v))
#pragma unroll
    for (int s = 0; s < 32; ++s) mx = fmaxf(mx, acc[s]);
    out_feats[(size_t)gid * H2_DIM + t] = mx;
  }
}

// ---------------------------------------------------------------------------
extern "C" void kernel_launch(void* const* d_in, const int* in_sizes, int n_in,
                              void* d_out, int out_size, void* d_ws, size_t ws_size,
                              hipStream_t stream) {
  const float* xyz   = (const float*)d_in[0];  // (4,16384,3) f32
  const float* feats = (const float*)d_in[1];  // (4,16384,64) f32
  // d_in[2] = bid (unused; output bid is all zeros)
  const float* w1 = (const float*)d_in[3];     // (67,64)
  const float* b1 = (const float*)d_in[4];     // (64,)
  const float* w2 = (const float*)d_in[5];     // (64,128)
  const float* b2 = (const float*)d_in[6];     // (128,)

  float* out       = (float*)d_out;
  float* out_xyz   = out;                                        // (4,2048,3)
  float* out_feats = out + (size_t)B_SZ * M_CENT * 3;            // (4,2048,128)
  float* out_bid   = out_feats + (size_t)B_SZ * M_CENT * H2_DIM; // (4,2048,1) int32 zeros
  int*   idx_ws    = (int*)d_ws;                                 // (4,2048,32) int32, 1 MiB

  hipLaunchKernelGGL(fps_kernel, dim3(B_SZ), dim3(FPS_T), 0, stream, xyz, out_xyz);
  hipLaunchKernelGGL(ballq_kernel, dim3((B_SZ * M_CENT + 3) / 4), dim3(256), 0, stream,
                     xyz, out_xyz, idx_ws);
  hipLaunchKernelGGL(mlp_kernel, dim3(B_SZ * M_CENT), dim3(128), 0, stream,
                     xyz, feats, out_xyz, idx_ws, w1, b1, w2, b2, out_feats);
  hipMemsetAsync(out_bid, 0, (size_t)B_SZ * M_CENT * sizeof(int), stream);
}

// Round 4
// 3595.910 us; speedup vs baseline: 1.1570x; 1.0312x over previous
//
#include <hip/hip_runtime.h>
#include <cstdint>
#include <cstddef>

#define B_SZ   4
#define N_PTS  16384
#define M_CENT 2048
#define NSAMP  32
#define C_IN   64
#define H1_DIM 64
#define H2_DIM 128
#define FPS_T  512
#define PPT    (N_PTS / FPS_T)   // 32 points per thread
#define PAIRS  (PPT / 2)         // 16 SoA float2 pairs per thread
#define H0_STR 68                // 67 channels padded to 68 for 16B-aligned float4

typedef float v2f __attribute__((ext_vector_type(2)));

// u64 max with neighbor fetched via DPP (both 32-bit halves move from the same
// source lane; invalid lanes keep 'old' = self, i.e. identity under max).
// ~5 VALU per level at VALU latency -- replaces __shfl_xor's 2 ds_bpermute
// per level at ~LDS latency. HW-verified (round-3 kernel passed).
template <int CTRL>
__device__ __forceinline__ unsigned long long kmax_dpp(unsigned long long k) {
  const int lo  = (int)(unsigned)(k & 0xFFFFFFFFULL);
  const int hi  = (int)(unsigned)(k >> 32);
  const int olo = __builtin_amdgcn_update_dpp(lo, lo, CTRL, 0xF, 0xF, false);
  const int ohi = __builtin_amdgcn_update_dpp(hi, hi, CTRL, 0xF, 0xF, false);
  const unsigned long long o =
      ((unsigned long long)(unsigned)ohi << 32) | (unsigned)olo;
  return (o > k) ? o : k;
}

// ---------------------------------------------------------------------------
// K1: Farthest-point sampling. One block per batch, 512 thr x 32 pts.
// WHY 512/launch_bounds(512,1): a 1024-thr block structurally caps the
// unified reg budget at 128/wave (16 waves => 4 waves/SIMD => 512/4); peak
// pressure (64 state + temps) > 128 made the allocator AGPR-home the coord
// arrays, and every in-loop use paid accvgpr copies (~250 wasted VALU
// instr/thread/iter; rounds 0-3 all hit this, VGPR_Count 84/44/40 < state).
// At 512 thr + minwaves=1 the budget is 512; state = 96 coord + 32 pd = 128
// floats + temps ~= 200 < 256 arch VGPRs -> no pressure, no AGPR traffic.
// Init-only asm pins stop load rematerialization (round-2 pathology); NO
// per-iteration pins (round-3 lesson: they force copies, not residency).
// Reduction: DPP u64-max (ROW_SHR 1/2/4/8 + BCAST15/31 -> lane63; cross-wave
// via LDS + ROW_SHR 1/2/4 over 8 partials -> readlane 7) -- u64 (dist,
// N-idx) key, bit-identical argmax (max dist, min idx on tie).
// Distance math: pk sub/mul/add/min, exact per element, numpy op order, no FMA.
// ---------------------------------------------------------------------------
__global__ __launch_bounds__(FPS_T, 1) void fps_kernel(const float* __restrict__ xyz,
                                                       float* __restrict__ out_xyz) {
#pragma clang fp contract(off)
  const int b    = blockIdx.x;
  const int t    = threadIdx.x;
  const int lane = t & 63;
  const int wave = t >> 6;           // 8 waves
  const float* bx = xyz + (size_t)b * N_PTS * 3;
  float* ox = out_xyz + (size_t)b * M_CENT * 3;

  v2f px[PAIRS], py[PAIRS], pz[PAIRS], pdp[PAIRS];
#pragma unroll
  for (int k = 0; k < PAIRS; ++k) {
    const int i0 = (2 * k + 0) * FPS_T + t;
    const int i1 = (2 * k + 1) * FPS_T + t;
    v2f vx, vy, vz;
    vx.x = bx[i0 * 3 + 0]; vx.y = bx[i1 * 3 + 0];
    vy.x = bx[i0 * 3 + 1]; vy.y = bx[i1 * 3 + 1];
    vz.x = bx[i0 * 3 + 2]; vz.y = bx[i1 * 3 + 2];
    px[k] = vx; py[k] = vy; pz[k] = vz;
    v2f big; big.x = 1e10f; big.y = 1e10f;  // BIG
    pdp[k] = big;
  }
  // Init-only pin: coords now opaque-defined -> loads cannot be sunk back
  // into the m-loop. (No per-iteration pins: they force copies, round 3.)
  asm volatile("" : "+v"(px[0]), "+v"(px[1]), "+v"(px[2]),  "+v"(px[3]),
                    "+v"(px[4]), "+v"(px[5]), "+v"(px[6]),  "+v"(px[7]),
                    "+v"(px[8]), "+v"(px[9]), "+v"(px[10]), "+v"(px[11]),
                    "+v"(px[12]),"+v"(px[13]),"+v"(px[14]), "+v"(px[15]));
  asm volatile("" : "+v"(py[0]), "+v"(py[1]), "+v"(py[2]),  "+v"(py[3]),
                    "+v"(py[4]), "+v"(py[5]), "+v"(py[6]),  "+v"(py[7]),
                    "+v"(py[8]), "+v"(py[9]), "+v"(py[10]), "+v"(py[11]),
                    "+v"(py[12]),"+v"(py[13]),"+v"(py[14]), "+v"(py[15]));
  asm volatile("" : "+v"(pz[0]), "+v"(pz[1]), "+v"(pz[2]),  "+v"(pz[3]),
                    "+v"(pz[4]), "+v"(pz[5]), "+v"(pz[6]),  "+v"(pz[7]),
                    "+v"(pz[8]), "+v"(pz[9]), "+v"(pz[10]), "+v"(pz[11]),
                    "+v"(pz[12]),"+v"(pz[13]),"+v"(pz[14]), "+v"(pz[15]));

  __shared__ unsigned long long s_key[2][8];

  int cur = 0;  // reference idx0 = 0
  for (int m = 0; m < M_CENT; ++m) {
    const int curs = __builtin_amdgcn_readfirstlane(cur);  // uniform -> SGPR path
    const float cx = bx[curs * 3 + 0];                     // L2-hot broadcast
    const float cy = bx[curs * 3 + 1];
    const float cz = bx[curs * 3 + 2];
    if (t == 0) { ox[m * 3 + 0] = cx; ox[m * 3 + 1] = cy; ox[m * 3 + 2] = cz; }
    if (m == M_CENT - 1) break;

    v2f vcx, vcy, vcz;
    vcx.x = cx; vcx.y = cx;
    vcy.x = cy; vcy.y = cy;
    vcz.x = cz; vcz.y = cz;
    float bv = -1.0f;  // dists >= 0, so first point always taken
    int   bi = 0;
#pragma unroll
    for (int k = 0; k < PAIRS; ++k) {
      const v2f dx = px[k] - vcx;         // v_pk_sub_f32 (exact per element)
      const v2f dy = py[k] - vcy;
      const v2f dz = pz[k] - vcz;
      const v2f sx = dx * dx;             // v_pk_mul_f32
      const v2f sy = dy * dy;
      const v2f sz = dz * dz;
      const v2f s1 = sx + sy;             // v_pk_add_f32 -> (dx2+dy2)
      const v2f d2 = s1 + sz;             // -> (dx2+dy2)+dz2  (numpy op order, no FMA)
      v2f nd = pdp[k];
      nd.x = fminf(nd.x, d2.x);           // v_pk_min_f32 (no NaNs: sums of squares)
      nd.y = fminf(nd.y, d2.y);
      pdp[k] = nd;
      // strict >: keeps smaller k (= smaller global idx) on ties within thread
      const bool c0 = nd.x > bv;
      bv = c0 ? nd.x : bv;
      bi = c0 ? ((2 * k + 0) * FPS_T + t) : bi;
      const bool c1 = nd.y > bv;
      bv = c1 ? nd.y : bv;
      bi = c1 ? ((2 * k + 1) * FPS_T + t) : bi;
    }
    // pack: high = float bits (>=0, monotone), low = N-idx so ties -> min idx
    unsigned long long key = ((unsigned long long)__float_as_uint(bv) << 32)
                           | (unsigned int)(N_PTS - bi);
    // intra-wave max -> lane 63 (other lanes hold partial maxes; only 63 used)
    key = kmax_dpp<0x111>(key);   // row_shr:1
    key = kmax_dpp<0x112>(key);   // row_shr:2
    key = kmax_dpp<0x114>(key);   // row_shr:4
    key = kmax_dpp<0x118>(key);   // row_shr:8
    key = kmax_dpp<0x142>(key);   // row_bcast15
    key = kmax_dpp<0x143>(key);   // row_bcast31
    const int p = m & 1;
    if (lane == 63) s_key[p][wave] = key;
    __syncthreads();
    // all waves redundantly reduce the 8 per-wave keys (no 2nd barrier):
    // each 16-lane row loads the 8 partials, ROW_SHR tree -> lane 7.
    unsigned long long k2 = s_key[p][lane & 7];
    k2 = kmax_dpp<0x111>(k2);
    k2 = kmax_dpp<0x112>(k2);
    k2 = kmax_dpp<0x114>(k2);
    const int lo7 = __builtin_amdgcn_readlane((int)(unsigned)(k2 & 0xFFFFFFFFULL), 7);
    cur = N_PTS - lo7;
  }
}

// ---------------------------------------------------------------------------
// K2: Ball query. One wave per centroid: ballot + prefix popcount appends the
// first 32 in-radius indices in index order (== top_k(-order) semantics),
// pads with the first hit. Early exit once 32 found.
// ---------------------------------------------------------------------------
__global__ __launch_bounds__(256) void ballq_kernel(const float* __restrict__ xyz,
                                                    const float* __restrict__ new_xyz,
                                                    int* __restrict__ idx_out) {
#pragma clang fp contract(off)
  const int lane = threadIdx.x & 63;
  const int gid  = blockIdx.x * 4 + (threadIdx.x >> 6);
  if (gid >= B_SZ * M_CENT) return;
  const int b = gid >> 11;  // / M_CENT
  const float* bx = xyz + (size_t)b * N_PTS * 3;
  const float cx = new_xyz[gid * 3 + 0];
  const float cy = new_xyz[gid * 3 + 1];
  const float cz = new_xyz[gid * 3 + 2];
  const float rr = (float)(0.8 * 0.8);  // double 0.64 -> f32 (JAX weak-scalar cast)
  int* out = idx_out + (size_t)gid * NSAMP;

  int count = 0;
  int first = -1;
  for (int base = 0; base < N_PTS; base += 64) {
    const int i = base + lane;
    const float dx = bx[i * 3 + 0] - cx;
    const float dy = bx[i * 3 + 1] - cy;
    const float dz = bx[i * 3 + 2] - cz;
    const float d = (dx * dx + dy * dy) + dz * dz;
    const bool pred = d < rr;
    const unsigned long long mk = __ballot(pred);
    if (pred) {
      const int slot = count + __popcll(mk & ((1ULL << lane) - 1ULL));
      if (slot < NSAMP) out[slot] = i;
    }
    if (first < 0 && mk != 0ULL) first = base + (__ffsll((long long)mk) - 1);
    count += __popcll(mk);
    if (count >= NSAMP) break;
  }
  if (count < NSAMP) {
    for (int k = count + lane; k < NSAMP; k += 64) out[k] = first;  // centroid itself is a hit
  }
}

// ---------------------------------------------------------------------------
// K3: gather + MLP(67->64 relu, 64->128 relu) + max over 32 samples.
// One 128-thread block per centroid. h0/h1 staged in LDS; reads are
// wave-uniform float4 broadcasts; weights coalesced from L1/L2.
// ---------------------------------------------------------------------------
__global__ __launch_bounds__(128) void mlp_kernel(const float* __restrict__ xyz,
                                                  const float* __restrict__ feats,
                                                  const float* __restrict__ new_xyz,
                                                  const int* __restrict__ idx,
                                                  const float* __restrict__ w1,
                                                  const float* __restrict__ b1,
                                                  const float* __restrict__ w2,
                                                  const float* __restrict__ b2,
                                                  float* __restrict__ out_feats) {
  const int gid = blockIdx.x;
  const int t   = threadIdx.x;
  const int b   = gid >> 11;  // / M_CENT

  __shared__ float h0[NSAMP * H0_STR];
  __shared__ float h1[NSAMP * H1_DIM];
  __shared__ int   sidx[NSAMP];

  if (t < NSAMP) sidx[t] = idx[(size_t)gid * NSAMP + t];
  const float cx = new_xyz[gid * 3 + 0];
  const float cy = new_xyz[gid * 3 + 1];
  const float cz = new_xyz[gid * 3 + 2];
  __syncthreads();

  const float* bxyz = xyz + (size_t)b * N_PTS * 3;
  const float* bft  = feats + (size_t)b * N_PTS * C_IN;
  for (int e = t; e < NSAMP * 67; e += 128) {
    const int s = e / 67;
    const int c = e - s * 67;
    const int p = sidx[s];
    float v;
    if (c < 3) {
      const float pc = bxyz[p * 3 + c];
      v = pc - (c == 0 ? cx : (c == 1 ? cy : cz));
    } else {
      v = bft[(size_t)p * C_IN + (c - 3)];
    }
    h0[s * H0_STR + c] = v;
  }
  __syncthreads();

  // layer 1: col = t&63 over H1_DIM, half = t>>6 picks 16 of 32 samples
  {
    const int col  = t & 63;
    const int half = t >> 6;
    float acc[16];
    const float bb = b1[col];
#pragma unroll
    for (int s = 0; s < 16; ++s) acc[s] = bb;
    const float* h0base = h0 + (half * 16) * H0_STR;
    for (int k = 0; k < 64; k += 4) {
      const float w0v = w1[(k + 0) * H1_DIM + col];
      const float w1v = w1[(k + 1) * H1_DIM + col];
      const float w2v = w1[(k + 2) * H1_DIM + col];
      const float w3v = w1[(k + 3) * H1_DIM + col];
#pragma unroll
      for (int s = 0; s < 16; ++s) {
        const float4 h4 = *reinterpret_cast<const float4*>(h0base + s * H0_STR + k);
        acc[s] += h4.x * w0v + h4.y * w1v + h4.z * w2v + h4.w * w3v;
      }
    }
    for (int k = 64; k < 67; ++k) {
      const float wv = w1[k * H1_DIM + col];
#pragma unroll
      for (int s = 0; s < 16; ++s) acc[s] += h0base[s * H0_STR + k] * wv;
    }
#pragma unroll
    for (int s = 0; s < 16; ++s) h1[(half * 16 + s) * H1_DIM + col] = fmaxf(acc[s], 0.0f);
  }
  __syncthreads();

  // layer 2 + max-pool: col = t over H2_DIM
  {
    float acc[32];
    const float bb = b2[t];
#pragma unroll
    for (int s = 0; s < 32; ++s) acc[s] = bb;
    for (int k = 0; k < 64; k += 4) {
      const float w0v = w2[(k + 0) * H2_DIM + t];
      const float w1v = w2[(k + 1) * H2_DIM + t];
      const float w2v = w2[(k + 2) * H2_DIM + t];
      const float w3v = w2[(k + 3) * H2_DIM + t];
#pragma unroll
      for (int s = 0; s < 32; ++s) {
        const float4 h4 = *reinterpret_cast<const float4*>(&h1[s * H1_DIM + k]);
        acc[s] += h4.x * w0v + h4.y * w1v + h4.z * w2v + h4.w * w3v;
      }
    }
    float mx = 0.0f;  // max(relu(v)) == max(0, max(v))
#pragma unroll
    for (int s = 0; s < 32; ++s) mx = fmaxf(mx, acc[s]);
    out_feats[(size_t)gid * H2_DIM + t] = mx;
  }
}

// ---------------------------------------------------------------------------
extern "C" void kernel_launch(void* const* d_in, const int* in_sizes, int n_in,
                              void* d_out, int out_size, void* d_ws, size_t ws_size,
                              hipStream_t stream) {
  const float* xyz   = (const float*)d_in[0];  // (4,16384,3) f32
  const float* feats = (const float*)d_in[1];  // (4,16384,64) f32
  // d_in[2] = bid (unused; output bid is all zeros)
  const float* w1 = (const float*)d_in[3];     // (67,64)
  const float* b1 = (const float*)d_in[4];     // (64,)
  const float* w2 = (const float*)d_in[5];     // (64,128)
  const float* b2 = (const float*)d_in[6];     // (128,)

  float* out       = (float*)d_out;
  float* out_xyz   = out;                                        // (4,2048,3)
  float* out_feats = out + (size_t)B_SZ * M_CENT * 3;            // (4,2048,128)
  float* out_bid   = out_feats + (size_t)B_SZ * M_CENT * H2_DIM; // (4,2048,1) int32 zeros
  int*   idx_ws    = (int*)d_ws;                                 // (4,2048,32) int32, 1 MiB

  hipLaunchKernelGGL(fps_kernel, dim3(B_SZ), dim3(FPS_T), 0, stream, xyz, out_xyz);
  hipLaunchKernelGGL(ballq_kernel, dim3((B_SZ * M_CENT + 3) / 4), dim3(256), 0, stream,
                     xyz, out_xyz, idx_ws);
  hipLaunchKernelGGL(mlp_kernel, dim3(B_SZ * M_CENT), dim3(128), 0, stream,
                     xyz, feats, out_xyz, idx_ws, w1, b1, w2, b2, out_feats);
  hipMemsetAsync(out_bid, 0, (size_t)B_SZ * M_CENT * sizeof(int), stream);
}